// Round 3
// baseline (785.265 us; speedup 1.0000x reference)
//
#include <hip/hip_runtime.h>
#include <math.h>

#define NCLASS 10
#define NFEAT  64
#define K1D_BPC 64     // blocks per class in k1d

// workspace layout (4-byte units)
#define OFF_M    0                // [10][64][64] float, atomic accum
#define OFF_S    40960            // [10][64] float, atomic accum
#define OFF_CNT  41600            // [10] int, histogram counts
#define OFF_CURS 41616            // [10] int, scatter cursors
#define OFF_PADO 41632            // [11] int, padded class offsets
#define OFF_LDC  41648            // [10] float
#define OFF_PM   41664            // [45] float
#define OFF_PL   41712            // [45] float
#define OFF_SIDX 41760            // [N + 640] int, class-sorted row indices
#define ZERO_CNT 41616            // zero M, S, CNT

// ---------------------------------------------------------------- k0: zero accumulators
__global__ void k0_zero(float* __restrict__ ws) {
  int i = blockIdx.x * blockDim.x + threadIdx.x;
  if (i < ZERO_CNT) ws[i] = 0.0f;
}

// ---------------------------------------------------------------- k1a: class histogram
__global__ __launch_bounds__(256) void k1a_hist(const int* __restrict__ T,
                                                float* __restrict__ ws, int N) {
  __shared__ int h[NCLASS];
  if (threadIdx.x < NCLASS) h[threadIdx.x] = 0;
  __syncthreads();
  int stride = gridDim.x * blockDim.x;
  for (int i = blockIdx.x * blockDim.x + threadIdx.x; i < N; i += stride)
    atomicAdd(&h[T[i]], 1);
  __syncthreads();
  if (threadIdx.x < NCLASS)
    atomicAdd((int*)(ws + OFF_CNT) + threadIdx.x, h[threadIdx.x]);
}

// ---------------------------------------------------------------- k1b: offsets + cursors
__global__ void k1b_scan(float* __restrict__ ws) {
  if (threadIdx.x == 0) {
    const int* cnt = (const int*)(ws + OFF_CNT);
    int* pado = (int*)(ws + OFF_PADO);
    int* curs = (int*)(ws + OFF_CURS);
    int acc = 0;
    for (int c = 0; c < NCLASS; ++c) {
      pado[c] = acc; curs[c] = acc;
      acc += (cnt[c] + 63) & ~63;     // pad each class to batch multiple
    }
    pado[NCLASS] = acc;
  }
}

// ---------------------------------------------------------------- k1c: counting-sort scatter
#define K1C_RPB 1024
__global__ __launch_bounds__(256) void k1c_scatter(const int* __restrict__ T,
                                                   float* __restrict__ ws, int N) {
  __shared__ int lcnt[NCLASS], lbase[NCLASS];
  int* curs = (int*)(ws + OFF_CURS);
  int* sidx = (int*)(ws + OFF_SIDX);
  if (threadIdx.x < NCLASS) lcnt[threadIdx.x] = 0;
  __syncthreads();
  int start = blockIdx.x * K1C_RPB;
  int end = start + K1C_RPB; if (end > N) end = N;
  int t[4], rank[4];
#pragma unroll
  for (int u = 0; u < 4; ++u) {
    int i = start + u * 256 + threadIdx.x;
    if (i < end) { t[u] = T[i]; rank[u] = atomicAdd(&lcnt[t[u]], 1); }
  }
  __syncthreads();
  if (threadIdx.x < NCLASS)
    lbase[threadIdx.x] = atomicAdd(&curs[threadIdx.x], lcnt[threadIdx.x]);
  __syncthreads();
#pragma unroll
  for (int u = 0; u < 4; ++u) {
    int i = start + u * 256 + threadIdx.x;
    if (i < end) sidx[lbase[t[u]] + rank[u]] = i;
  }
}

// ---------------------------------------------------------------- k1d: dense per-class Gram
// grid = (K1D_BPC, NCLASS), block = 256 (4 waves). All waves of grid.y handle class c.
// Wave processes 64-row batches of the class-sorted index list: static loop bounds,
// addresses available ahead -> compiler can pipeline the broadcast float4 loads.
// Lane j accumulates column j of M[c] in registers; block-reduces via LDS atomics,
// then one atomic global partial per block.
__global__ __launch_bounds__(256) void k1d_gram(const float* __restrict__ X,
                                                float* __restrict__ ws) {
  const int* cnts = (const int*)(ws + OFF_CNT);
  const int* pado = (const int*)(ws + OFF_PADO);
  const int* sidx = (const int*)(ws + OFF_SIDX);
  const int c    = blockIdx.y;
  const int wv   = threadIdx.x >> 6;
  const int lane = threadIdx.x & 63;
  const int cnt  = cnts[c];
  const int base = pado[c];
  const int nBatch = (cnt + 63) >> 6;
  const int wgid = blockIdx.x * 4 + wv;      // 0..255 within class
  const int WSTRIDE = K1D_BPC * 4;

  float acc[64];
#pragma unroll
  for (int r = 0; r < 64; ++r) acc[r] = 0.0f;
  float accS = 0.0f;

  for (int b = wgid; b < nBatch; b += WSTRIDE) {
    int p = (b << 6) + lane;
    int myidx = (p < cnt) ? sidx[base + p] : 0;   // coalesced
    int rmax = cnt - (b << 6); if (rmax > 64) rmax = 64;
#pragma unroll 2
    for (int r = 0; r < rmax; ++r) {
      int idxr = __shfl(myidx, r, 64);            // wave-uniform row index
      const float*  row  = X + (size_t)idxr * NFEAT;
      const float4* row4 = (const float4*)row;
      float vx = row[lane];                       // coalesced 256B
      accS += vx;
#pragma unroll
      for (int k = 0; k < 16; ++k) {              // wave-uniform broadcast loads
        float4 bb = row4[k];
        acc[4*k+0] += bb.x * vx;
        acc[4*k+1] += bb.y * vx;
        acc[4*k+2] += bb.z * vx;
        acc[4*k+3] += bb.w * vx;
      }
    }
  }

  // block reduction: LDS atomics into a single 16.6 KB buffer
  __shared__ float Ms[64][65];
  __shared__ float Ssum[64];
  for (int e = threadIdx.x; e < 4096; e += 256) Ms[e >> 6][e & 63] = 0.0f;
  if (threadIdx.x < 64) Ssum[threadIdx.x] = 0.0f;
  __syncthreads();
#pragma unroll
  for (int r = 0; r < 64; ++r) atomicAdd(&Ms[r][lane], acc[r]);
  atomicAdd(&Ssum[lane], accS);
  __syncthreads();

  float* M = ws + OFF_M + c * 4096;
  for (int e = threadIdx.x; e < 4096; e += 256)
    atomicAdd(&M[e], Ms[e >> 6][e & 63]);
  if (threadIdx.x < 64)
    atomicAdd(&ws[OFF_S + c * 64 + threadIdx.x], Ssum[threadIdx.x]);
}

// ---------------------------------------------------------------- k2b: Cholesky blocks
// Builds Sc on the fly from raw moments (k2a folded in).
// blocks 0..9: logdet(Sc[c]).  blocks 10..54: pair (i<j): Spair=0.5(Sc_i+Sc_j),
// logdet_pair and maha = |L^{-1} dmu|^2 / 8.  Single wave per block.
__global__ void k2b_chol(float* __restrict__ ws) {
  __shared__ float S[64][65];
  __shared__ float ybuf[64];
  __shared__ float mubi[64], mubj[64];
  const int lane = threadIdx.x;
  const int bid  = blockIdx.x;

  int ci, cj, p = -1;
  bool isPair = (bid >= NCLASS);
  if (!isPair) { ci = cj = bid; }
  else {
    p = bid - NCLASS;
    int rem = p, i = 0;
    while (rem >= 9 - i) { rem -= 9 - i; ++i; }
    ci = i; cj = i + 1 + rem;
  }

  const int* cnts = (const int*)(ws + OFF_CNT);
  float cnti = (float)cnts[ci], cntj = (float)cnts[cj];
  float mui = ws[OFF_S + ci * 64 + lane] / cnti;
  float muj = ws[OFF_S + cj * 64 + lane] / cntj;
  mubi[lane] = mui; mubj[lane] = muj;
  __syncthreads();

  const float* Mi = ws + OFF_M + ci * 4096;
  const float* Mj = ws + OFF_M + cj * 4096;
  float invi = 1.0f / (cnti - 1.0f), invj = 1.0f / (cntj - 1.0f);
  for (int r = 0; r < 64; ++r) {
    float v = (Mi[r * 64 + lane] - cnti * mubi[r] * mui) * invi;
    if (isPair) {
      float scj = (Mj[r * 64 + lane] - cntj * mubj[r] * muj) * invj;
      v = 0.5f * (v + scj);
    }
    S[r][lane] = v;
  }
  float d = isPair ? (mui - muj) : 0.0f;
  __syncthreads();

  // in-place lower Cholesky (right-looking)
  for (int k = 0; k < 64; ++k) {
    float Lkk = sqrtf(S[k][k]);
    float Lik = 0.0f;
    if (lane > k) Lik = S[lane][k] / Lkk;
    __syncthreads();
    if (lane == k) S[k][k] = Lkk;
    if (lane > k)  S[lane][k] = Lik;
    __syncthreads();
    for (int j = k + 1; j <= lane; ++j)
      S[lane][j] -= Lik * S[j][k];
    __syncthreads();
  }

  float lv = logf(S[lane][lane]);
#pragma unroll
  for (int off = 32; off > 0; off >>= 1) lv += __shfl_down(lv, off, 64);

  if (isPair) {
    float pi = d;
    for (int k = 0; k < 64; ++k) {
      if (lane == k) ybuf[k] = pi / S[k][k];
      __syncthreads();
      float yk = ybuf[k];
      if (lane > k) pi -= S[lane][k] * yk;
      __syncthreads();
    }
    float yv = ybuf[lane];
    float s2 = yv * yv;
#pragma unroll
    for (int off = 32; off > 0; off >>= 1) s2 += __shfl_down(s2, off, 64);
    if (lane == 0) {
      ws[OFF_PM + p] = s2 * 0.125f;
      ws[OFF_PL + p] = 2.0f * lv;
    }
  } else {
    if (lane == 0) ws[OFF_LDC + bid] = 2.0f * lv;
  }
}

// ---------------------------------------------------------------- k2c: final scalar
__global__ void k2c_final(const float* __restrict__ Ksamp,
                          const float* __restrict__ ws,
                          float* __restrict__ out) {
  __shared__ double ldc[10], pm[45], pl[45];
  __shared__ double Km[100], Sp[100], L[100], Inv[100], Aa[100];
  __shared__ double ldSp_s, trace_s, ldK_s;
  const int tid = threadIdx.x;
  const int k = 10;

  if (tid < 10) ldc[tid] = (double)ws[OFF_LDC + tid];
  if (tid < 45) { pm[tid] = (double)ws[OFF_PM + tid]; pl[tid] = (double)ws[OFF_PL + tid]; }
  if (tid < 100) Sp[tid] = (double)Ksamp[tid];
  __syncthreads();

  double s00 = Sp[0];
  if (tid < 100) {
    int i = tid / 10, j = tid % 10;
    double Kv;
    if (i == j) Kv = s00;
    else {
      int a = i < j ? i : j, b = i < j ? j : i;
      int pp = (a * (19 - a)) / 2 + (b - a - 1);
      double D = pm[pp] + 0.5 * (pl[pp] - 0.5 * (ldc[i] + ldc[j]));
      Kv = s00 * (0.5 * exp(-D * D * 100.0));
    }
    Km[tid] = Kv;
    Aa[tid] = Kv;
  }
  __syncthreads();

  for (int kk = 0; kk < k; ++kk) {
    if (tid == kk) {
      double s = Sp[kk * k + kk];
      for (int m = 0; m < kk; ++m) s -= L[kk * k + m] * L[kk * k + m];
      L[kk * k + kk] = sqrt(s);
    }
    __syncthreads();
    if (tid > kk && tid < k) {
      double v = Sp[tid * k + kk];
      for (int m = 0; m < kk; ++m) v -= L[tid * k + m] * L[kk * k + m];
      L[tid * k + kk] = v / L[kk * k + kk];
    }
    __syncthreads();
  }
  if (tid == 0) {
    double s = 0.0;
    for (int kk = 0; kk < k; ++kk) s += 2.0 * log(L[kk * k + kk]);
    ldSp_s = s;
  }

  if (tid < k) {
    double y[10], x[10];
    for (int r = 0; r < k; ++r) {
      double v = (r == tid) ? 1.0 : 0.0;
      for (int m = 0; m < r; ++m) v -= L[r * k + m] * y[m];
      y[r] = v / L[r * k + r];
    }
    for (int r = k - 1; r >= 0; --r) {
      double v = y[r];
      for (int m = r + 1; m < k; ++m) v -= L[m * k + r] * x[m];
      x[r] = v / L[r * k + r];
    }
    for (int r = 0; r < k; ++r) Inv[r * k + tid] = x[r];
  }
  __syncthreads();
  if (tid == 0) {
    double t = 0.0;
    for (int e = 0; e < 100; ++e) t += Inv[e] * Km[e];
    trace_s = t;
    ldK_s = 0.0;
  }
  __syncthreads();

  for (int kk = 0; kk < k; ++kk) {
    if (tid == 0) {
      int piv = kk; double mx = fabs(Aa[kk * k + kk]);
      for (int r = kk + 1; r < k; ++r) {
        double v = fabs(Aa[r * k + kk]);
        if (v > mx) { mx = v; piv = r; }
      }
      if (piv != kk)
        for (int c2 = 0; c2 < k; ++c2) {
          double tmp = Aa[kk * k + c2]; Aa[kk * k + c2] = Aa[piv * k + c2]; Aa[piv * k + c2] = tmp;
        }
      ldK_s += log(fabs(Aa[kk * k + kk]));
    }
    __syncthreads();
    if (tid < 100) {
      int r = tid / 10, c2 = tid % 10;
      if (r > kk && c2 > kk)
        Aa[r * k + c2] -= Aa[r * k + kk] / Aa[kk * k + kk] * Aa[kk * k + c2];
    }
    __syncthreads();
  }

  if (tid == 0)
    out[0] = (float)(0.5 * (trace_s - (double)k + ldSp_s - ldK_s));
}

// ---------------------------------------------------------------- launch
extern "C" void kernel_launch(void* const* d_in, const int* in_sizes, int n_in,
                              void* d_out, int out_size, void* d_ws, size_t ws_size,
                              hipStream_t stream) {
  const float* X  = (const float*)d_in[0];
  const int*   T  = (const int*)d_in[1];
  const float* Ks = (const float*)d_in[2];
  float* out = (float*)d_out;
  float* ws  = (float*)d_ws;
  int N = in_sizes[1];

  k0_zero<<<(ZERO_CNT + 255) / 256, 256, 0, stream>>>(ws);
  k1a_hist<<<256, 256, 0, stream>>>(T, ws, N);
  k1b_scan<<<1, 64, 0, stream>>>(ws);
  k1c_scatter<<<(N + K1C_RPB - 1) / K1C_RPB, 256, 0, stream>>>(T, ws, N);
  k1d_gram<<<dim3(K1D_BPC, NCLASS), 256, 0, stream>>>(X, ws);
  k2b_chol<<<55, 64, 0, stream>>>(ws);
  k2c_final<<<1, 128, 0, stream>>>(Ks, ws, out);
}

// Round 4
// 388.107 us; speedup vs baseline: 2.0233x; 2.0233x over previous
//
#include <hip/hip_runtime.h>
#include <math.h>

#define NCLASS  10
#define NFEAT   64
#define CHUNK   1024          // rows per hist/scatter chunk
#define NCHUNK_MAX 512        // N=524288 -> 512 chunks
#define K1D_BPC 104           // blocks per class in k1d

// ws layout (4-byte units)
#define OFF_M    0                        // [10][4096] float, atomic accum
#define OFF_S    40960                    // [10][64] float, atomic accum
#define OFF_CNT  41600                    // [10] int
#define OFF_PADO 41616                    // [11] int
#define OFF_LDC  41632                    // [10] float
#define OFF_PM   41648                    // [45] float
#define OFF_PL   41696                    // [45] float
#define OFF_HB   41744                    // [512][10] int: chunk-class counts -> bases
#define OFF_SIDX (OFF_HB + NCHUNK_MAX*NCLASS)   // [N+640] int
#define ZERO_CNT 41600                    // zero M + S

// ---------------------------------------------------------------- k1a: zero + per-chunk hist
__global__ __launch_bounds__(256) void k1a_hist(const int* __restrict__ T,
                                                float* __restrict__ ws, int N, int nchunk) {
  const int b = blockIdx.x, t = threadIdx.x;
  for (int z = b * 256 + t; z < ZERO_CNT; z += nchunk * 256) ws[z] = 0.0f;
  __shared__ int h[NCLASS];
  if (t < NCLASS) h[t] = 0;
  __syncthreads();
  int start = b * CHUNK;
#pragma unroll
  for (int u = 0; u < 4; ++u) {
    int i = start + u * 256 + t;
    if (i < N) atomicAdd(&h[T[i]], 1);
  }
  __syncthreads();
  if (t < NCLASS) ((int*)(ws + OFF_HB))[b * NCLASS + t] = h[t];
}

// ---------------------------------------------------------------- k1b: scan -> bases
__global__ void k1b_scan(float* __restrict__ ws, int nchunk) {
  __shared__ int H[NCHUNK_MAX * NCLASS];
  __shared__ int cnt[NCLASS];
  __shared__ int pado[NCLASS + 1];
  int* Hg = (int*)(ws + OFF_HB);
  for (int i = threadIdx.x; i < nchunk * NCLASS; i += blockDim.x) H[i] = Hg[i];
  __syncthreads();
  if (threadIdx.x < NCLASS) {
    int s = 0;
    for (int b = 0; b < nchunk; ++b) s += H[b * NCLASS + threadIdx.x];
    cnt[threadIdx.x] = s;
    ((int*)(ws + OFF_CNT))[threadIdx.x] = s;
  }
  __syncthreads();
  if (threadIdx.x == 0) {
    int a = 0;
    int* pg = (int*)(ws + OFF_PADO);
    for (int c = 0; c < NCLASS; ++c) { pado[c] = a; pg[c] = a; a += (cnt[c] + 63) & ~63; }
    pado[NCLASS] = a; pg[NCLASS] = a;
  }
  __syncthreads();
  if (threadIdx.x < NCLASS) {
    int run = pado[threadIdx.x];
    for (int b = 0; b < nchunk; ++b) {
      int v = H[b * NCLASS + threadIdx.x];
      Hg[b * NCLASS + threadIdx.x] = run;     // absolute base for chunk b, class c
      run += v;
    }
  }
}

// ---------------------------------------------------------------- k1c: deterministic-base scatter
__global__ __launch_bounds__(256) void k1c_scatter(const int* __restrict__ T,
                                                   float* __restrict__ ws, int N) {
  __shared__ int lcnt[NCLASS], lbase[NCLASS];
  const int b = blockIdx.x, t = threadIdx.x;
  if (t < NCLASS) { lcnt[t] = 0; lbase[t] = ((const int*)(ws + OFF_HB))[b * NCLASS + t]; }
  __syncthreads();
  int start = b * CHUNK;
  int tv[4], rk[4];
#pragma unroll
  for (int u = 0; u < 4; ++u) {
    int i = start + u * 256 + t;
    if (i < N) { tv[u] = T[i]; rk[u] = atomicAdd(&lcnt[tv[u]], 1); }
    else tv[u] = -1;
  }
  __syncthreads();
  int* sidx = (int*)(ws + OFF_SIDX);
#pragma unroll
  for (int u = 0; u < 4; ++u)
    if (tv[u] >= 0) sidx[lbase[tv[u]] + rk[u]] = start + u * 256 + t;
}

// ---------------------------------------------------------------- k1d: LDS-staged per-class Gram
// grid (K1D_BPC, NCLASS), block 256 = 4 waves. Double-buffered 64-row LDS batches.
// Lane (li,lj) owns an 8x8 tile of M[c]; waves K-split (16 rows each).
// Per row per wave: 4 ds_read_b128 + 64 v_fmac. Column sums fold into staging.
__global__ __launch_bounds__(256, 3) void k1d_gram(const float* __restrict__ X,
                                                   float* __restrict__ ws) {
  __shared__ float buf[2][4096];
  const int c    = blockIdx.y;
  const int t    = threadIdx.x;
  const int w    = t >> 6, lane = t & 63;
  const int li   = lane >> 3, lj = lane & 7;
  const int c4   = t & 15, rg = t >> 4;        // staging: col-group, row-group
  const int cnt  = ((const int*)(ws + OFF_CNT))[c];
  const int base = ((const int*)(ws + OFF_PADO))[c];
  const int* __restrict__ sidx = (const int*)(ws + OFF_SIDX);
  const float4* __restrict__ X4 = (const float4*)X;
  const int nb = (cnt + 63) >> 6;

  float acc[8][8];
#pragma unroll
  for (int i = 0; i < 8; ++i)
#pragma unroll
    for (int j = 0; j < 8; ++j) acc[i][j] = 0.0f;
  float4 csum = {0.f, 0.f, 0.f, 0.f};

  float4 st[4];
  const int myb = blockIdx.x;
  if (myb < nb) {
#pragma unroll
    for (int u = 0; u < 4; ++u) {
      int p = (myb << 6) + u * 16 + rg;
      float4 v = {0.f, 0.f, 0.f, 0.f};
      if (p < cnt) v = X4[(size_t)sidx[base + p] * 16 + c4];
      csum.x += v.x; csum.y += v.y; csum.z += v.z; csum.w += v.w;
      *(float4*)&buf[0][(u * 16 + rg) * 64 + c4 * 4] = v;
    }
  }

  int cur = 0;
  for (int b = myb; b < nb; b += K1D_BPC) {
    int nxt = b + K1D_BPC;
    __syncthreads();
    bool more = (nxt < nb);
    if (more) {                                  // prefetch next batch into regs
#pragma unroll
      for (int u = 0; u < 4; ++u) {
        int p = (nxt << 6) + u * 16 + rg;
        float4 v = {0.f, 0.f, 0.f, 0.f};
        if (p < cnt) v = X4[(size_t)sidx[base + p] * 16 + c4];
        csum.x += v.x; csum.y += v.y; csum.z += v.z; csum.w += v.w;
        st[u] = v;
      }
    }
    const float* __restrict__ B = buf[cur];
#pragma unroll 2
    for (int r16 = 0; r16 < 16; ++r16) {         // this wave's 16 rows of the batch
      const float* row = B + ((w << 4) + r16) * 64;
      float a0[8], b0[8];
      *(float4*)&a0[0] = *(const float4*)(row + li * 8);
      *(float4*)&a0[4] = *(const float4*)(row + li * 8 + 4);
      *(float4*)&b0[0] = *(const float4*)(row + lj * 8);
      *(float4*)&b0[4] = *(const float4*)(row + lj * 8 + 4);
#pragma unroll
      for (int i = 0; i < 8; ++i)
#pragma unroll
        for (int j = 0; j < 8; ++j)
          acc[i][j] += a0[i] * b0[j];
    }
    if (more) {
#pragma unroll
      for (int u = 0; u < 4; ++u)
        *(float4*)&buf[cur ^ 1][(u * 16 + rg) * 64 + c4 * 4] = st[u];
    }
    cur ^= 1;
  }
  __syncthreads();

  // merge: csum -> buf[1], acc tiles -> buf[0] (4 sequential wave passes)
  *(float4*)&buf[1][rg * 64 + c4 * 4] = csum;    // [16][64] partial col-sums
  float* R = buf[0];
  for (int ww = 0; ww < 4; ++ww) {
    if (w == ww) {
#pragma unroll
      for (int i = 0; i < 8; ++i)
#pragma unroll
        for (int j = 0; j < 8; ++j) {
          int ad = (li * 8 + i) * 64 + lj * 8 + j;
          if (ww == 0) R[ad] = acc[i][j]; else R[ad] += acc[i][j];
        }
    }
    __syncthreads();
  }

  float* M = ws + OFF_M + c * 4096;
  for (int e = t; e < 4096; e += 256) atomicAdd(&M[e], R[e]);
  if (t < 64) {
    float s = 0.0f;
#pragma unroll
    for (int g = 0; g < 16; ++g) s += buf[1][g * 64 + t];
    atomicAdd(&ws[OFF_S + c * 64 + t], s);
  }
}

// ---------------------------------------------------------------- k2b: Cholesky blocks
// Builds Sc on the fly from raw moments. blocks 0..9: logdet(Sc[c]).
// blocks 10..54: pair (i<j): Spair=0.5(Sc_i+Sc_j), logdet + maha=|L^{-1}dmu|^2/8.
__global__ void k2b_chol(float* __restrict__ ws) {
  __shared__ float S[64][65];
  __shared__ float ybuf[64];
  __shared__ float mubi[64], mubj[64];
  const int lane = threadIdx.x;
  const int bid  = blockIdx.x;

  int ci, cj, p = -1;
  bool isPair = (bid >= NCLASS);
  if (!isPair) { ci = cj = bid; }
  else {
    p = bid - NCLASS;
    int rem = p, i = 0;
    while (rem >= 9 - i) { rem -= 9 - i; ++i; }
    ci = i; cj = i + 1 + rem;
  }

  const int* cnts = (const int*)(ws + OFF_CNT);
  float cnti = (float)cnts[ci], cntj = (float)cnts[cj];
  float mui = ws[OFF_S + ci * 64 + lane] / cnti;
  float muj = ws[OFF_S + cj * 64 + lane] / cntj;
  mubi[lane] = mui; mubj[lane] = muj;
  __syncthreads();

  const float* Mi = ws + OFF_M + ci * 4096;
  const float* Mj = ws + OFF_M + cj * 4096;
  float invi = 1.0f / (cnti - 1.0f), invj = 1.0f / (cntj - 1.0f);
  for (int r = 0; r < 64; ++r) {
    float v = (Mi[r * 64 + lane] - cnti * mubi[r] * mui) * invi;
    if (isPair) {
      float scj = (Mj[r * 64 + lane] - cntj * mubj[r] * muj) * invj;
      v = 0.5f * (v + scj);
    }
    S[r][lane] = v;
  }
  float d = isPair ? (mui - muj) : 0.0f;
  __syncthreads();

  for (int k = 0; k < 64; ++k) {
    float Lkk = sqrtf(S[k][k]);
    float Lik = 0.0f;
    if (lane > k) Lik = S[lane][k] / Lkk;
    __syncthreads();
    if (lane == k) S[k][k] = Lkk;
    if (lane > k)  S[lane][k] = Lik;
    __syncthreads();
    for (int j = k + 1; j <= lane; ++j)
      S[lane][j] -= Lik * S[j][k];
    __syncthreads();
  }

  float lv = logf(S[lane][lane]);
#pragma unroll
  for (int off = 32; off > 0; off >>= 1) lv += __shfl_down(lv, off, 64);

  if (isPair) {
    float pi = d;
    for (int k = 0; k < 64; ++k) {
      if (lane == k) ybuf[k] = pi / S[k][k];
      __syncthreads();
      float yk = ybuf[k];
      if (lane > k) pi -= S[lane][k] * yk;
      __syncthreads();
    }
    float yv = ybuf[lane];
    float s2 = yv * yv;
#pragma unroll
    for (int off = 32; off > 0; off >>= 1) s2 += __shfl_down(s2, off, 64);
    if (lane == 0) {
      ws[OFF_PM + p] = s2 * 0.125f;
      ws[OFF_PL + p] = 2.0f * lv;
    }
  } else {
    if (lane == 0) ws[OFF_LDC + bid] = 2.0f * lv;
  }
}

// ---------------------------------------------------------------- k2c: final scalar
__global__ void k2c_final(const float* __restrict__ Ksamp,
                          const float* __restrict__ ws,
                          float* __restrict__ out) {
  __shared__ double ldc[10], pm[45], pl[45];
  __shared__ double Km[100], Sp[100], L[100], Inv[100], Aa[100];
  __shared__ double ldSp_s, trace_s, ldK_s;
  const int tid = threadIdx.x;
  const int k = 10;

  if (tid < 10) ldc[tid] = (double)ws[OFF_LDC + tid];
  if (tid < 45) { pm[tid] = (double)ws[OFF_PM + tid]; pl[tid] = (double)ws[OFF_PL + tid]; }
  if (tid < 100) Sp[tid] = (double)Ksamp[tid];
  __syncthreads();

  double s00 = Sp[0];
  if (tid < 100) {
    int i = tid / 10, j = tid % 10;
    double Kv;
    if (i == j) Kv = s00;
    else {
      int a = i < j ? i : j, b = i < j ? j : i;
      int pp = (a * (19 - a)) / 2 + (b - a - 1);
      double D = pm[pp] + 0.5 * (pl[pp] - 0.5 * (ldc[i] + ldc[j]));
      Kv = s00 * (0.5 * exp(-D * D * 100.0));
    }
    Km[tid] = Kv;
    Aa[tid] = Kv;
  }
  __syncthreads();

  for (int kk = 0; kk < k; ++kk) {
    if (tid == kk) {
      double s = Sp[kk * k + kk];
      for (int m = 0; m < kk; ++m) s -= L[kk * k + m] * L[kk * k + m];
      L[kk * k + kk] = sqrt(s);
    }
    __syncthreads();
    if (tid > kk && tid < k) {
      double v = Sp[tid * k + kk];
      for (int m = 0; m < kk; ++m) v -= L[tid * k + m] * L[kk * k + m];
      L[tid * k + kk] = v / L[kk * k + kk];
    }
    __syncthreads();
  }
  if (tid == 0) {
    double s = 0.0;
    for (int kk = 0; kk < k; ++kk) s += 2.0 * log(L[kk * k + kk]);
    ldSp_s = s;
  }

  if (tid < k) {
    double y[10], x[10];
    for (int r = 0; r < k; ++r) {
      double v = (r == tid) ? 1.0 : 0.0;
      for (int m = 0; m < r; ++m) v -= L[r * k + m] * y[m];
      y[r] = v / L[r * k + r];
    }
    for (int r = k - 1; r >= 0; --r) {
      double v = y[r];
      for (int m = r + 1; m < k; ++m) v -= L[m * k + r] * x[m];
      x[r] = v / L[r * k + r];
    }
    for (int r = 0; r < k; ++r) Inv[r * k + tid] = x[r];
  }
  __syncthreads();
  if (tid == 0) {
    double t = 0.0;
    for (int e = 0; e < 100; ++e) t += Inv[e] * Km[e];
    trace_s = t;
    ldK_s = 0.0;
  }
  __syncthreads();

  for (int kk = 0; kk < k; ++kk) {
    if (tid == 0) {
      int piv = kk; double mx = fabs(Aa[kk * k + kk]);
      for (int r = kk + 1; r < k; ++r) {
        double v = fabs(Aa[r * k + kk]);
        if (v > mx) { mx = v; piv = r; }
      }
      if (piv != kk)
        for (int c2 = 0; c2 < k; ++c2) {
          double tmp = Aa[kk * k + c2]; Aa[kk * k + c2] = Aa[piv * k + c2]; Aa[piv * k + c2] = tmp;
        }
      ldK_s += log(fabs(Aa[kk * k + kk]));
    }
    __syncthreads();
    if (tid < 100) {
      int r = tid / 10, c2 = tid % 10;
      if (r > kk && c2 > kk)
        Aa[r * k + c2] -= Aa[r * k + kk] / Aa[kk * k + kk] * Aa[kk * k + c2];
    }
    __syncthreads();
  }

  if (tid == 0)
    out[0] = (float)(0.5 * (trace_s - (double)k + ldSp_s - ldK_s));
}

// ---------------------------------------------------------------- launch
extern "C" void kernel_launch(void* const* d_in, const int* in_sizes, int n_in,
                              void* d_out, int out_size, void* d_ws, size_t ws_size,
                              hipStream_t stream) {
  const float* X  = (const float*)d_in[0];
  const int*   T  = (const int*)d_in[1];
  const float* Ks = (const float*)d_in[2];
  float* out = (float*)d_out;
  float* ws  = (float*)d_ws;
  int N = in_sizes[1];
  int nchunk = (N + CHUNK - 1) / CHUNK;   // 512 for N=524288 (fits NCHUNK_MAX)

  k1a_hist<<<nchunk, 256, 0, stream>>>(T, ws, N, nchunk);
  k1b_scan<<<1, 256, 0, stream>>>(ws, nchunk);
  k1c_scatter<<<nchunk, 256, 0, stream>>>(T, ws, N);
  k1d_gram<<<dim3(K1D_BPC, NCLASS), 256, 0, stream>>>(X, ws);
  k2b_chol<<<55, 64, 0, stream>>>(ws);
  k2c_final<<<1, 128, 0, stream>>>(Ks, ws, out);
}

// Round 5
// 317.096 us; speedup vs baseline: 2.4764x; 1.2239x over previous
//
#include <hip/hip_runtime.h>
#include <math.h>

#define NCLASS  10
#define NFEAT   64
#define CHUNK   1024          // rows per hist/scatter chunk
#define NCHUNK_MAX 512        // N=524288 -> 512 chunks
#define K1D_BPC 104           // blocks per class in k1d

// ws layout (4-byte units)
#define OFF_M    0                        // [10][4096] float, atomic accum
#define OFF_S    40960                    // [10][64] float, atomic accum
#define OFF_CNT  41600                    // [10] int
#define OFF_PADO 41616                    // [11] int
#define OFF_LDC  41632                    // [10] float
#define OFF_PM   41648                    // [45] float
#define OFF_PL   41696                    // [45] float
#define OFF_HB   41744                    // [10][512] int: per-class per-chunk counts -> bases
#define OFF_SIDX (OFF_HB + NCHUNK_MAX*NCLASS)   // [N+640] int
#define ZERO_CNT 41600                    // zero M + S

__device__ __forceinline__ float rlane(float v, int l) {
  return __int_as_float(__builtin_amdgcn_readlane(__float_as_int(v), l));
}

// ---------------------------------------------------------------- k1a: zero + per-chunk hist
__global__ __launch_bounds__(256) void k1a_hist(const int* __restrict__ T,
                                                float* __restrict__ ws, int N, int nchunk) {
  const int b = blockIdx.x, t = threadIdx.x;
  for (int z = b * 256 + t; z < ZERO_CNT; z += nchunk * 256) ws[z] = 0.0f;
  __shared__ int h[NCLASS];
  if (t < NCLASS) h[t] = 0;
  __syncthreads();
  int start = b * CHUNK;
#pragma unroll
  for (int u = 0; u < 4; ++u) {
    int i = start + u * 256 + t;
    if (i < N) atomicAdd(&h[T[i]], 1);
  }
  __syncthreads();
  if (t < NCLASS) ((int*)(ws + OFF_HB))[t * NCHUNK_MAX + b] = h[t];  // transposed
}

// ---------------------------------------------------------------- k1b: parallel scan -> bases
// 640 threads = 10 waves; wave w scans class w's 512 chunk-counts (8/lane + wave scan).
__global__ __launch_bounds__(640) void k1b_scan(float* __restrict__ ws, int nchunk) {
  const int w = threadIdx.x >> 6;
  const int l = threadIdx.x & 63;
  int* Hg = (int*)(ws + OFF_HB);
  __shared__ int tot[NCLASS];
  int v[8], pre[8];
  int lanesum = 0;
#pragma unroll
  for (int u = 0; u < 8; ++u) {
    int b = l * 8 + u;
    v[u] = (b < nchunk) ? Hg[w * NCHUNK_MAX + b] : 0;
    pre[u] = lanesum;
    lanesum += v[u];
  }
  int incl = lanesum;
#pragma unroll
  for (int off = 1; off < 64; off <<= 1) {
    int t2 = __shfl_up(incl, off, 64);
    if (l >= off) incl += t2;
  }
  int excl = incl - lanesum;
  int ctot = __shfl(incl, 63, 64);
  if (l == 0) tot[w] = ctot;
  __syncthreads();
  int pado = 0;
#pragma unroll
  for (int c = 0; c < NCLASS; ++c)
    if (c < w) pado += (tot[c] + 63) & ~63;
#pragma unroll
  for (int u = 0; u < 8; ++u) {
    int b = l * 8 + u;
    if (b < nchunk) Hg[w * NCHUNK_MAX + b] = pado + excl + pre[u];
  }
  if (l == 0) {
    ((int*)(ws + OFF_CNT))[w] = ctot;
    ((int*)(ws + OFF_PADO))[w] = pado;
    if (w == NCLASS - 1) ((int*)(ws + OFF_PADO))[NCLASS] = pado + ((ctot + 63) & ~63);
  }
}

// ---------------------------------------------------------------- k1c: deterministic-base scatter
__global__ __launch_bounds__(256) void k1c_scatter(const int* __restrict__ T,
                                                   float* __restrict__ ws, int N) {
  __shared__ int lcnt[NCLASS], lbase[NCLASS];
  const int b = blockIdx.x, t = threadIdx.x;
  if (t < NCLASS) { lcnt[t] = 0; lbase[t] = ((const int*)(ws + OFF_HB))[t * NCHUNK_MAX + b]; }
  __syncthreads();
  int start = b * CHUNK;
  int tv[4], rk[4];
#pragma unroll
  for (int u = 0; u < 4; ++u) {
    int i = start + u * 256 + t;
    if (i < N) { tv[u] = T[i]; rk[u] = atomicAdd(&lcnt[tv[u]], 1); }
    else tv[u] = -1;
  }
  __syncthreads();
  int* sidx = (int*)(ws + OFF_SIDX);
#pragma unroll
  for (int u = 0; u < 4; ++u)
    if (tv[u] >= 0) sidx[lbase[tv[u]] + rk[u]] = start + u * 256 + t;
}

// ---------------------------------------------------------------- k1d: LDS-staged per-class Gram
__global__ __launch_bounds__(256, 3) void k1d_gram(const float* __restrict__ X,
                                                   float* __restrict__ ws) {
  __shared__ float buf[2][4096];
  const int c    = blockIdx.y;
  const int t    = threadIdx.x;
  const int w    = t >> 6, lane = t & 63;
  const int li   = lane >> 3, lj = lane & 7;
  const int c4   = t & 15, rg = t >> 4;
  const int cnt  = ((const int*)(ws + OFF_CNT))[c];
  const int base = ((const int*)(ws + OFF_PADO))[c];
  const int* __restrict__ sidx = (const int*)(ws + OFF_SIDX);
  const float4* __restrict__ X4 = (const float4*)X;
  const int nb = (cnt + 63) >> 6;

  float acc[8][8];
#pragma unroll
  for (int i = 0; i < 8; ++i)
#pragma unroll
    for (int j = 0; j < 8; ++j) acc[i][j] = 0.0f;
  float4 csum = {0.f, 0.f, 0.f, 0.f};

  float4 st[4];
  const int myb = blockIdx.x;
  if (myb < nb) {
#pragma unroll
    for (int u = 0; u < 4; ++u) {
      int p = (myb << 6) + u * 16 + rg;
      float4 v = {0.f, 0.f, 0.f, 0.f};
      if (p < cnt) v = X4[(size_t)sidx[base + p] * 16 + c4];
      csum.x += v.x; csum.y += v.y; csum.z += v.z; csum.w += v.w;
      *(float4*)&buf[0][(u * 16 + rg) * 64 + c4 * 4] = v;
    }
  }

  int cur = 0;
  for (int b = myb; b < nb; b += K1D_BPC) {
    int nxt = b + K1D_BPC;
    __syncthreads();
    bool more = (nxt < nb);
    if (more) {
#pragma unroll
      for (int u = 0; u < 4; ++u) {
        int p = (nxt << 6) + u * 16 + rg;
        float4 v = {0.f, 0.f, 0.f, 0.f};
        if (p < cnt) v = X4[(size_t)sidx[base + p] * 16 + c4];
        csum.x += v.x; csum.y += v.y; csum.z += v.z; csum.w += v.w;
        st[u] = v;
      }
    }
    const float* __restrict__ B = buf[cur];
#pragma unroll 2
    for (int r16 = 0; r16 < 16; ++r16) {
      const float* row = B + ((w << 4) + r16) * 64;
      float a0[8], b0[8];
      *(float4*)&a0[0] = *(const float4*)(row + li * 8);
      *(float4*)&a0[4] = *(const float4*)(row + li * 8 + 4);
      *(float4*)&b0[0] = *(const float4*)(row + lj * 8);
      *(float4*)&b0[4] = *(const float4*)(row + lj * 8 + 4);
#pragma unroll
      for (int i = 0; i < 8; ++i)
#pragma unroll
        for (int j = 0; j < 8; ++j)
          acc[i][j] += a0[i] * b0[j];
    }
    if (more) {
#pragma unroll
      for (int u = 0; u < 4; ++u)
        *(float4*)&buf[cur ^ 1][(u * 16 + rg) * 64 + c4 * 4] = st[u];
    }
    cur ^= 1;
  }
  __syncthreads();

  *(float4*)&buf[1][rg * 64 + c4 * 4] = csum;
  float* R = buf[0];
  for (int ww = 0; ww < 4; ++ww) {
    if (w == ww) {
#pragma unroll
      for (int i = 0; i < 8; ++i)
#pragma unroll
        for (int j = 0; j < 8; ++j) {
          int ad = (li * 8 + i) * 64 + lj * 8 + j;
          if (ww == 0) R[ad] = acc[i][j]; else R[ad] += acc[i][j];
        }
    }
    __syncthreads();
  }

  float* M = ws + OFF_M + c * 4096;
  for (int e = t; e < 4096; e += 256) atomicAdd(&M[e], R[e]);
  if (t < 64) {
    float s = 0.0f;
#pragma unroll
    for (int g = 0; g < 16; ++g) s += buf[1][g * 64 + t];
    atomicAdd(&ws[OFF_S + c * 64 + t], s);
  }
}

// ---------------------------------------------------------------- k2b: register Cholesky
// Lane i holds row i of S in 64 VGPRs; fully-unrolled k-loop with v_readlane column
// broadcasts (no LDS in hot loop -> no RMW latency chain). Solve + logdet fused in.
// Above-diagonal lanes hold garbage that provably never feeds valid lanes.
__global__ __launch_bounds__(64) void k2b_chol(float* __restrict__ ws) {
  __shared__ float Sld[64][65];
  __shared__ float mub[2][64];
  const int lane = threadIdx.x;
  const int bid  = blockIdx.x;

  int ci, cj, p = -1;
  bool isPair = (bid >= NCLASS);
  if (!isPair) { ci = cj = bid; }
  else {
    p = bid - NCLASS;
    int rem = p, i = 0;
    while (rem >= 9 - i) { rem -= 9 - i; ++i; }
    ci = i; cj = i + 1 + rem;
  }

  const int* cnts = (const int*)(ws + OFF_CNT);
  float cnti = (float)cnts[ci], cntj = (float)cnts[cj];
  float mui = ws[OFF_S + ci * 64 + lane] / cnti;
  float muj = ws[OFF_S + cj * 64 + lane] / cntj;
  mub[0][lane] = mui; mub[1][lane] = muj;
  __syncthreads();

  const float* Mi = ws + OFF_M + ci * 4096;
  const float* Mj = ws + OFF_M + cj * 4096;
  float invi = 1.0f / (cnti - 1.0f), invj = 1.0f / (cntj - 1.0f);
  for (int r = 0; r < 64; ++r) {
    float v = (Mi[r * 64 + lane] - cnti * mub[0][r] * mui) * invi;
    if (isPair) v = 0.5f * (v + (Mj[r * 64 + lane] - cntj * mub[1][r] * muj) * invj);
    Sld[r][lane] = v;
  }
  float pi = isPair ? (mui - muj) : 0.0f;
  __syncthreads();

  float S[64];
#pragma unroll
  for (int q = 0; q < 16; ++q)
    *(float4*)&S[q * 4] = *(const float4*)&Sld[lane][q * 4];

  float logacc = 0.0f, s2 = 0.0f;
#pragma unroll
  for (int k = 0; k < 64; ++k) {
    float lkk = sqrtf(rlane(S[k], k));      // uniform diag
    float inv = 1.0f / lkk;
    float lik = S[k] * inv;                 // L[i][k] for i>=k
    S[k] = lik;
    logacc += logf(lkk);                    // redundant in all lanes
    float yk = rlane(pi, k) * inv;          // forward-solve step (uniform)
    s2 += yk * yk;
    pi -= (lane > k) ? lik * yk : 0.0f;
#pragma unroll
    for (int j = k + 1; j < 64; ++j)
      S[j] -= lik * rlane(lik, j);          // rank-1 update, SGPR broadcast
  }

  if (lane == 0) {
    if (isPair) {
      ws[OFF_PM + p] = s2 * 0.125f;
      ws[OFF_PL + p] = 2.0f * logacc;
    } else {
      ws[OFF_LDC + bid] = 2.0f * logacc;
    }
  }
}

// ---------------------------------------------------------------- k2c: final scalar (float, parallel)
__global__ void k2c_final(const float* __restrict__ Ksamp,
                          const float* __restrict__ ws,
                          float* __restrict__ out) {
  __shared__ float ldc[10], pm[45], pl[45];
  __shared__ float Km[100], Sp[100], L[100], Inv[100], Aa[100];
  __shared__ float red[3];   // 0: ldSp, 1: trace, 2: ldK
  const int tid = threadIdx.x;
  const int k = 10;

  if (tid < 3) red[tid] = 0.0f;
  if (tid < 10) ldc[tid] = ws[OFF_LDC + tid];
  if (tid < 45) { pm[tid] = ws[OFF_PM + tid]; pl[tid] = ws[OFF_PL + tid]; }
  if (tid < 100) Sp[tid] = Ksamp[tid];
  __syncthreads();

  float s00 = Sp[0];
  if (tid < 100) {
    int i = tid / 10, j = tid % 10;
    float Kv;
    if (i == j) Kv = s00;
    else {
      int a = i < j ? i : j, b = i < j ? j : i;
      int pp = (a * (19 - a)) / 2 + (b - a - 1);
      float D = pm[pp] + 0.5f * (pl[pp] - 0.5f * (ldc[i] + ldc[j]));
      Kv = s00 * 0.5f * expf(-D * D * 100.0f);
    }
    Km[tid] = Kv;
    Aa[tid] = Kv;
  }
  __syncthreads();

  for (int kk = 0; kk < k; ++kk) {
    if (tid == kk) {
      float s = Sp[kk * k + kk];
      for (int m = 0; m < kk; ++m) s -= L[kk * k + m] * L[kk * k + m];
      L[kk * k + kk] = sqrtf(s);
    }
    __syncthreads();
    if (tid > kk && tid < k) {
      float v = Sp[tid * k + kk];
      for (int m = 0; m < kk; ++m) v -= L[tid * k + m] * L[kk * k + m];
      L[tid * k + kk] = v / L[kk * k + kk];
    }
    __syncthreads();
  }
  if (tid < k) atomicAdd(&red[0], 2.0f * logf(L[tid * k + tid]));

  if (tid < k) {
    float y[10], x[10];
    for (int r = 0; r < k; ++r) {
      float v = (r == tid) ? 1.0f : 0.0f;
      for (int m = 0; m < r; ++m) v -= L[r * k + m] * y[m];
      y[r] = v / L[r * k + r];
    }
    for (int r = k - 1; r >= 0; --r) {
      float v = y[r];
      for (int m = r + 1; m < k; ++m) v -= L[m * k + r] * x[m];
      x[r] = v / L[r * k + r];
    }
    for (int r = 0; r < k; ++r) Inv[r * k + tid] = x[r];
  }
  __syncthreads();
  if (tid < 100) atomicAdd(&red[1], Inv[tid] * Km[tid]);

  for (int kk = 0; kk < k; ++kk) {
    if (tid == 0) {
      int piv = kk; float mx = fabsf(Aa[kk * k + kk]);
      for (int r = kk + 1; r < k; ++r) {
        float v = fabsf(Aa[r * k + kk]);
        if (v > mx) { mx = v; piv = r; }
      }
      if (piv != kk)
        for (int c2 = 0; c2 < k; ++c2) {
          float tmp = Aa[kk * k + c2]; Aa[kk * k + c2] = Aa[piv * k + c2]; Aa[piv * k + c2] = tmp;
        }
      red[2] += logf(fabsf(Aa[kk * k + kk]));
    }
    __syncthreads();
    if (tid < 100) {
      int r = tid / 10, c2 = tid % 10;
      if (r > kk && c2 > kk)
        Aa[r * k + c2] -= Aa[r * k + kk] / Aa[kk * k + kk] * Aa[kk * k + c2];
    }
    __syncthreads();
  }

  if (tid == 0)
    out[0] = 0.5f * (red[1] - (float)k + red[0] - red[2]);
}

// ---------------------------------------------------------------- launch
extern "C" void kernel_launch(void* const* d_in, const int* in_sizes, int n_in,
                              void* d_out, int out_size, void* d_ws, size_t ws_size,
                              hipStream_t stream) {
  const float* X  = (const float*)d_in[0];
  const int*   T  = (const int*)d_in[1];
  const float* Ks = (const float*)d_in[2];
  float* out = (float*)d_out;
  float* ws  = (float*)d_ws;
  int N = in_sizes[1];
  int nchunk = (N + CHUNK - 1) / CHUNK;

  k1a_hist<<<nchunk, 256, 0, stream>>>(T, ws, N, nchunk);
  k1b_scan<<<1, 640, 0, stream>>>(ws, nchunk);
  k1c_scatter<<<nchunk, 256, 0, stream>>>(T, ws, N);
  k1d_gram<<<dim3(K1D_BPC, NCLASS), 256, 0, stream>>>(X, ws);
  k2b_chol<<<55, 64, 0, stream>>>(ws);
  k2c_final<<<1, 128, 0, stream>>>(Ks, ws, out);
}